// Round 13
// baseline (177.428 us; speedup 1.0000x reference)
//
#include <hip/hip_runtime.h>

#define BDIM 256
#define KC_STRIDE 28                  // per (case,co): K[0..24], bias at [25], 2 pad
#define CASE_STRIDE (32 * KC_STRIDE)  // 896 floats per border-case
#define SP 2052                       // S plane stride (floats), padded (2052%32==4)

// case index along one axis: 0 (p==0), 1 (p==1), 2 (interior), 3 (p==62), 4 (p==63)
__device__ __forceinline__ int casef(int p) {
  return ((unsigned)(p - 2) < 60u) ? 2 : (p < 2 ? p : p - 59);
}

// ---------------- prep: collapsed 5x5 kernels, layout [case][co][28] ----------------
__global__ __launch_bounds__(BDIM) void prep_kernel(
    const float* __restrict__ W1, const float* __restrict__ b1,
    const float* __restrict__ W2, const float* __restrict__ b2,
    float* __restrict__ ws) {
  __shared__ float Mlds[9 * 9 * 32];
  __shared__ float BvL[9 * 32];
  const int tid = threadIdx.x;
  const int co = tid & 31;
  for (int tap = tid >> 5; tap < 9; tap += 8) {
    float acc[9] = {0.f, 0.f, 0.f, 0.f, 0.f, 0.f, 0.f, 0.f, 0.f};
    float accB = 0.f;
    for (int ci = 0; ci < 64; ++ci) {
      float w2 = W2[(tap * 64 + ci) * 32 + co];
      accB = fmaf(b1[ci], w2, accB);
#pragma unroll
      for (int e = 0; e < 9; ++e) acc[e] = fmaf(W1[e * 64 + ci], w2, acc[e]);
    }
#pragma unroll
    for (int e = 0; e < 9; ++e) Mlds[(tap * 9 + e) * 32 + co] = acc[e];
    BvL[tap * 32 + co] = accB;
  }
  __syncthreads();

  const int a = blockIdx.x / 5, c = blockIdx.x % 5;
  const int dmask[5] = {4, 6, 7, 3, 1};
  const int Da = dmask[a], Dc = dmask[c];
  for (int t = tid; t < CASE_STRIDE; t += BDIM) {
    int cc = t / KC_STRIDE, r = t % KC_STRIDE;
    float s = 0.f;
    if (r < 25) {
      int u = r / 5, v = r % 5;
      for (int di = 0; di < 3; ++di) {
        if (!((Da >> di) & 1)) continue;
        int ei = u - di;
        if ((unsigned)ei > 2u) continue;
        for (int dj = 0; dj < 3; ++dj) {
          if (!((Dc >> dj) & 1)) continue;
          int ej = v - dj;
          if ((unsigned)ej > 2u) continue;
          s += Mlds[((di * 3 + dj) * 9 + ei * 3 + ej) * 32 + cc];
        }
      }
    } else if (r == 25) {
      s = b2[cc];
      for (int di = 0; di < 3; ++di)
        if ((Da >> di) & 1)
          for (int dj = 0; dj < 3; ++dj)
            if ((Dc >> dj) & 1) s += BvL[(di * 3 + dj) * 32 + cc];
    }
    ws[blockIdx.x * CASE_STRIDE + t] = s;
  }
}

// Compute one channel-group stage into S (champion-identical compute).
__device__ __forceinline__ void compute_stage(
    int cg, int nqi, int nqb, int r0, int tid,
    const unsigned short* aq, const float* xp, const float* KiL,
    const float* ws, float* S) {
  // ---- interior quads: item = (quad, co4); K scalar reads from LDS ----
  for (int n = tid; n < nqi * 4; n += BDIM) {
    int g = aq[n >> 2];
    int co4 = n & 3;
    int co = (cg << 2) + co4;
    int k = g >> 4, q0 = (g & 15) << 2;
    const float* Kp = &KiL[co * KC_STRIDE];
    float bias = Kp[25];
    float z0 = bias, z1 = bias, z2 = bias, z3 = bias;
#pragma unroll
    for (int u = 0; u < 5; ++u) {
      const float* xr = &xp[(k + u) * 68 + q0];
      float4 xa = *reinterpret_cast<const float4*>(xr);
      float4 xc = *reinterpret_cast<const float4*>(xr + 4);
      float xv[8] = {xa.x, xa.y, xa.z, xa.w, xc.x, xc.y, xc.z, xc.w};
#pragma unroll
      for (int v = 0; v < 5; ++v) {
        float Kv = Kp[u * 5 + v];
        z0 = fmaf(xv[v], Kv, z0);
        z1 = fmaf(xv[v + 1], Kv, z1);
        z2 = fmaf(xv[v + 2], Kv, z2);
        z3 = fmaf(xv[v + 3], Kv, z3);
      }
    }
    *reinterpret_cast<float4*>(&S[co4 * SP + (k << 6) + q0]) =
        make_float4(z0, z1, z2, z3);
  }
  // ---- border quads: per-pixel case, K scalar reads from global (L2-hot) ----
  for (int n = tid; n < nqb * 4; n += BDIM) {
    int g = aq[511 - (n >> 2)];
    int co4 = n & 3;
    int co = (cg << 2) + co4;
    int k = g >> 4, q0 = (g & 15) << 2;
    int p = r0 + k;
    int cp = casef(p);
    const float* K0 = ws + ((cp * 5 + casef(q0)) * 32 + co) * KC_STRIDE;
    const float* K1 = ws + ((cp * 5 + casef(q0 + 1)) * 32 + co) * KC_STRIDE;
    const float* K2 = ws + ((cp * 5 + casef(q0 + 2)) * 32 + co) * KC_STRIDE;
    const float* K3 = ws + ((cp * 5 + casef(q0 + 3)) * 32 + co) * KC_STRIDE;
    float z0 = K0[25], z1 = K1[25], z2 = K2[25], z3 = K3[25];
#pragma unroll
    for (int u = 0; u < 5; ++u) {
      const float* xr = &xp[(k + u) * 68 + q0];
      float4 xa = *reinterpret_cast<const float4*>(xr);
      float4 xc = *reinterpret_cast<const float4*>(xr + 4);
      float xv[8] = {xa.x, xa.y, xa.z, xa.w, xc.x, xc.y, xc.z, xc.w};
#pragma unroll
      for (int v = 0; v < 5; ++v) {
        int o = u * 5 + v;
        z0 = fmaf(xv[v], K0[o], z0);
        z1 = fmaf(xv[v + 1], K1[o], z1);
        z2 = fmaf(xv[v + 2], K2[o], z2);
        z3 = fmaf(xv[v + 3], K3[o], z3);
      }
    }
    *reinterpret_cast<float4*>(&S[co4 * SP + (k << 6) + q0]) =
        make_float4(z0, z1, z2, z3);
  }
}

// ---- main: champion + dbuf dump registers (WAR decoupling) + stage rotation ----
__global__ __launch_bounds__(BDIM) void main_kernel(
    const float* __restrict__ x, const float* __restrict__ ws,
    float* __restrict__ out) {
  const int bb = blockIdx.x;
  const int b = bb >> 1;
  const int r0 = (bb & 1) << 5;  // 0 or 32
  const int tid = threadIdx.x;
  const int lane = tid & 63;
  const int wave = tid >> 6;

  __shared__ __align__(16) float xp[36 * 68];      // rows r0-2..r0+33, cols -2..65
  __shared__ __align__(16) float S[4 * SP];        // 4 channel-planes of 32x64, padded
  __shared__ __align__(16) float KiL[CASE_STRIDE]; // interior case (2,2)
  __shared__ unsigned long long Rm[32];
  __shared__ unsigned short aq[512];  // interior from 0 up, border from 511 down
  __shared__ int nqi_sh, nqb_sh;

  if (tid == 0) { nqi_sh = 0; nqb_sh = 0; }
  float4* xp4 = reinterpret_cast<float4*>(xp);
  for (int i = tid; i < 612; i += BDIM) xp4[i] = make_float4(0.f, 0.f, 0.f, 0.f);
  for (int i = tid; i < CASE_STRIDE; i += BDIM) KiL[i] = ws[12 * CASE_STRIDE + i];
  __syncthreads();

  const float* xb = x + (size_t)b * 4096;
  for (int it = tid; it < 576; it += BDIM) {
    int i = it >> 4, c4 = (it & 15) << 2;
    int r = r0 - 2 + i;
    if ((unsigned)r < 64u) {
      float4 v = *reinterpret_cast<const float4*>(xb + r * 64 + c4);
      float2* d2 = reinterpret_cast<float2*>(&xp[i * 68 + 2 + c4]);
      d2[0] = make_float2(v.x, v.y);
      d2[1] = make_float2(v.z, v.w);
    }
  }
  __syncthreads();

  for (int k = wave; k < 32; k += 4) {
    int pred = (xp[(k + 2) * 68 + 2 + lane] != 0.0f);
    unsigned long long m = __ballot(pred);
    if (lane == 0) Rm[k] = m;
  }
  __syncthreads();

  for (int g = tid; g < 512; g += BDIM) {
    int k = g >> 4, q0 = (g & 15) << 2;
    unsigned bits = (unsigned)(Rm[k] >> q0) & 0xFu;
    if (!bits) continue;
    int p = r0 + k;
    bool inter = ((unsigned)(p - 2) < 60u) && ((unsigned)(q0 - 4) <= 52u);
    if (inter) {
      int idx = atomicAdd(&nqi_sh, 1);
      aq[idx] = (unsigned short)g;
    } else {
      int idx = atomicAdd(&nqb_sh, 1);
      aq[511 - idx] = (unsigned short)g;
    }
  }
  __syncthreads();

  const int nqi = nqi_sh, nqb = nqb_sh;
  float* outb = out + (size_t)b * (32 * 4096);
  const int rot = bb & 7;  // per-block stage rotation (stages are independent)

  for (int s2 = 0; s2 < 4; ++s2) {
    // =================== STAGE A (dump register set dA) ===================
    const int cgA = ((s2 << 1) + rot) & 7;
    compute_stage(cgA, nqi, nqb, r0, tid, aq, xp, KiL, ws, S);
    asm volatile("s_waitcnt lgkmcnt(0)" ::: "memory");
    __builtin_amdgcn_s_barrier();
    float4 dA[8];
    {
      const float4* Sp = reinterpret_cast<const float4*>(&S[wave * SP]);
#pragma unroll
      for (int i = 0; i < 8; ++i) dA[i] = Sp[(i << 6) + lane];
      int co = (cgA << 2) + wave;
      float* dst = outb + (((size_t)co) << 12) + (r0 << 6);
#pragma unroll
      for (int i = 0; i < 8; ++i) {
        int idx4 = (i << 6) + lane;
        int k = idx4 >> 4, q0 = (idx4 & 15) << 2;
        unsigned bits = (unsigned)(Rm[k] >> q0) & 0xFu;
        if (!(bits & 1u)) dA[i].x = 0.f;
        if (!(bits & 2u)) dA[i].y = 0.f;
        if (!(bits & 4u)) dA[i].z = 0.f;
        if (!(bits & 8u)) dA[i].w = 0.f;
        *reinterpret_cast<float4*>(dst + (idx4 << 2)) = dA[i];
      }
    }
    asm volatile("s_waitcnt lgkmcnt(0)" ::: "memory");
    __builtin_amdgcn_s_barrier();

    // =================== STAGE B (dump register set dB) ===================
    const int cgB = ((s2 << 1) + 1 + rot) & 7;
    compute_stage(cgB, nqi, nqb, r0, tid, aq, xp, KiL, ws, S);
    asm volatile("s_waitcnt lgkmcnt(0)" ::: "memory");
    __builtin_amdgcn_s_barrier();
    float4 dB[8];
    {
      const float4* Sp = reinterpret_cast<const float4*>(&S[wave * SP]);
#pragma unroll
      for (int i = 0; i < 8; ++i) dB[i] = Sp[(i << 6) + lane];
      int co = (cgB << 2) + wave;
      float* dst = outb + (((size_t)co) << 12) + (r0 << 6);
#pragma unroll
      for (int i = 0; i < 8; ++i) {
        int idx4 = (i << 6) + lane;
        int k = idx4 >> 4, q0 = (idx4 & 15) << 2;
        unsigned bits = (unsigned)(Rm[k] >> q0) & 0xFu;
        if (!(bits & 1u)) dB[i].x = 0.f;
        if (!(bits & 2u)) dB[i].y = 0.f;
        if (!(bits & 4u)) dB[i].z = 0.f;
        if (!(bits & 8u)) dB[i].w = 0.f;
        *reinterpret_cast<float4*>(dst + (idx4 << 2)) = dB[i];
      }
    }
    asm volatile("s_waitcnt lgkmcnt(0)" ::: "memory");
    __builtin_amdgcn_s_barrier();
  }
}

extern "C" void kernel_launch(void* const* d_in, const int* in_sizes, int n_in,
                              void* d_out, int out_size, void* d_ws, size_t ws_size,
                              hipStream_t stream) {
  const float* x  = (const float*)d_in[0];
  const float* W1 = (const float*)d_in[1];
  const float* b1 = (const float*)d_in[2];
  const float* W2 = (const float*)d_in[3];
  const float* b2 = (const float*)d_in[4];
  float* out = (float*)d_out;
  float* ws  = (float*)d_ws;
  int B = in_sizes[0] / 4096;  // 1024 images of 64x64x1

  hipLaunchKernelGGL(prep_kernel, dim3(25), dim3(BDIM), 0, stream, W1, b1, W2, b2, ws);
  hipLaunchKernelGGL(main_kernel, dim3(2 * B), dim3(BDIM), 0, stream, x, ws, out);
}

// Round 15
// 145.935 us; speedup vs baseline: 1.2158x; 1.2158x over previous
//
#include <hip/hip_runtime.h>

#define BDIM 256
#define KC_STRIDE 28                  // per (case,co): K[0..24], bias at [25], 2 pad
#define CASE_STRIDE (32 * KC_STRIDE)  // 896 floats per border-case
#define SP 2052                       // S plane stride (floats), padded (2052%32==4)

typedef float floatx4 __attribute__((ext_vector_type(4)));

// case index along one axis: 0 (p==0), 1 (p==1), 2 (interior), 3 (p==62), 4 (p==63)
__device__ __forceinline__ int casef(int p) {
  return ((unsigned)(p - 2) < 60u) ? 2 : (p < 2 ? p : p - 59);
}

// ---------------- prep: collapsed 5x5 kernels, layout [case][co][28] ----------------
__global__ __launch_bounds__(BDIM) void prep_kernel(
    const float* __restrict__ W1, const float* __restrict__ b1,
    const float* __restrict__ W2, const float* __restrict__ b2,
    float* __restrict__ ws) {
  __shared__ float Mlds[9 * 9 * 32];
  __shared__ float BvL[9 * 32];
  const int tid = threadIdx.x;
  const int co = tid & 31;
  for (int tap = tid >> 5; tap < 9; tap += 8) {
    float acc[9] = {0.f, 0.f, 0.f, 0.f, 0.f, 0.f, 0.f, 0.f, 0.f};
    float accB = 0.f;
    for (int ci = 0; ci < 64; ++ci) {
      float w2 = W2[(tap * 64 + ci) * 32 + co];
      accB = fmaf(b1[ci], w2, accB);
#pragma unroll
      for (int e = 0; e < 9; ++e) acc[e] = fmaf(W1[e * 64 + ci], w2, acc[e]);
    }
#pragma unroll
    for (int e = 0; e < 9; ++e) Mlds[(tap * 9 + e) * 32 + co] = acc[e];
    BvL[tap * 32 + co] = accB;
  }
  __syncthreads();

  const int a = blockIdx.x / 5, c = blockIdx.x % 5;
  const int dmask[5] = {4, 6, 7, 3, 1};
  const int Da = dmask[a], Dc = dmask[c];
  for (int t = tid; t < CASE_STRIDE; t += BDIM) {
    int cc = t / KC_STRIDE, r = t % KC_STRIDE;
    float s = 0.f;
    if (r < 25) {
      int u = r / 5, v = r % 5;
      for (int di = 0; di < 3; ++di) {
        if (!((Da >> di) & 1)) continue;
        int ei = u - di;
        if ((unsigned)ei > 2u) continue;
        for (int dj = 0; dj < 3; ++dj) {
          if (!((Dc >> dj) & 1)) continue;
          int ej = v - dj;
          if ((unsigned)ej > 2u) continue;
          s += Mlds[((di * 3 + dj) * 9 + ei * 3 + ej) * 32 + cc];
        }
      }
    } else if (r == 25) {
      s = b2[cc];
      for (int di = 0; di < 3; ++di)
        if ((Da >> di) & 1)
          for (int dj = 0; dj < 3; ++dj)
            if ((Dc >> dj) & 1) s += BvL[(di * 3 + dj) * 32 + cc];
    }
    ws[blockIdx.x * CASE_STRIDE + t] = s;
  }
}

// ---- main: R6/R11 champion; ONLY change = nontemporal dump stores ----
__global__ __launch_bounds__(BDIM) void main_kernel(
    const float* __restrict__ x, const float* __restrict__ ws,
    float* __restrict__ out) {
  const int bb = blockIdx.x;
  const int b = bb >> 1;
  const int r0 = (bb & 1) << 5;  // 0 or 32
  const int tid = threadIdx.x;
  const int lane = tid & 63;
  const int wave = tid >> 6;

  __shared__ __align__(16) float xp[36 * 68];      // rows r0-2..r0+33, cols -2..65
  __shared__ __align__(16) float S[4 * SP];        // 4 channel-planes of 32x64, padded
  __shared__ __align__(16) float KiL[CASE_STRIDE]; // interior case (2,2)
  __shared__ unsigned long long Rm[32];
  __shared__ unsigned short aq[512];  // interior from 0 up, border from 511 down
  __shared__ int nqi_sh, nqb_sh;

  if (tid == 0) { nqi_sh = 0; nqb_sh = 0; }
  float4* xp4 = reinterpret_cast<float4*>(xp);
  for (int i = tid; i < 612; i += BDIM) xp4[i] = make_float4(0.f, 0.f, 0.f, 0.f);
  for (int i = tid; i < CASE_STRIDE; i += BDIM) KiL[i] = ws[12 * CASE_STRIDE + i];
  __syncthreads();

  const float* xb = x + (size_t)b * 4096;
  for (int it = tid; it < 576; it += BDIM) {
    int i = it >> 4, c4 = (it & 15) << 2;
    int r = r0 - 2 + i;
    if ((unsigned)r < 64u) {
      float4 v = *reinterpret_cast<const float4*>(xb + r * 64 + c4);
      float2* d2 = reinterpret_cast<float2*>(&xp[i * 68 + 2 + c4]);
      d2[0] = make_float2(v.x, v.y);
      d2[1] = make_float2(v.z, v.w);
    }
  }
  __syncthreads();

  for (int k = wave; k < 32; k += 4) {
    int pred = (xp[(k + 2) * 68 + 2 + lane] != 0.0f);
    unsigned long long m = __ballot(pred);
    if (lane == 0) Rm[k] = m;
  }
  __syncthreads();

  for (int g = tid; g < 512; g += BDIM) {
    int k = g >> 4, q0 = (g & 15) << 2;
    unsigned bits = (unsigned)(Rm[k] >> q0) & 0xFu;
    if (!bits) continue;
    int p = r0 + k;
    bool inter = ((unsigned)(p - 2) < 60u) && ((unsigned)(q0 - 4) <= 52u);
    if (inter) {
      int idx = atomicAdd(&nqi_sh, 1);
      aq[idx] = (unsigned short)g;
    } else {
      int idx = atomicAdd(&nqb_sh, 1);
      aq[511 - idx] = (unsigned short)g;
    }
  }
  __syncthreads();

  const int nqi = nqi_sh, nqb = nqb_sh;
  float* outb = out + (size_t)b * (32 * 4096);

  for (int s = 0; s < 8; ++s) {
    // ---- interior quads: item = (quad, co4); K scalar reads from LDS ----
    for (int n = tid; n < nqi * 4; n += BDIM) {
      int g = aq[n >> 2];
      int co4 = n & 3;
      int co = (s << 2) + co4;
      int k = g >> 4, q0 = (g & 15) << 2;
      const float* Kp = &KiL[co * KC_STRIDE];
      float bias = Kp[25];
      float z0 = bias, z1 = bias, z2 = bias, z3 = bias;
#pragma unroll
      for (int u = 0; u < 5; ++u) {
        const float* xr = &xp[(k + u) * 68 + q0];
        float4 xa = *reinterpret_cast<const float4*>(xr);
        float4 xc = *reinterpret_cast<const float4*>(xr + 4);
        float xv[8] = {xa.x, xa.y, xa.z, xa.w, xc.x, xc.y, xc.z, xc.w};
#pragma unroll
        for (int v = 0; v < 5; ++v) {
          float Kv = Kp[u * 5 + v];
          z0 = fmaf(xv[v], Kv, z0);
          z1 = fmaf(xv[v + 1], Kv, z1);
          z2 = fmaf(xv[v + 2], Kv, z2);
          z3 = fmaf(xv[v + 3], Kv, z3);
        }
      }
      *reinterpret_cast<float4*>(&S[co4 * SP + (k << 6) + q0]) =
          make_float4(z0, z1, z2, z3);
    }
    // ---- border quads: per-pixel case, K scalar reads from global (L2-hot) ----
    for (int n = tid; n < nqb * 4; n += BDIM) {
      int g = aq[511 - (n >> 2)];
      int co4 = n & 3;
      int co = (s << 2) + co4;
      int k = g >> 4, q0 = (g & 15) << 2;
      int p = r0 + k;
      int cp = casef(p);
      const float* K0 = ws + ((cp * 5 + casef(q0)) * 32 + co) * KC_STRIDE;
      const float* K1 = ws + ((cp * 5 + casef(q0 + 1)) * 32 + co) * KC_STRIDE;
      const float* K2 = ws + ((cp * 5 + casef(q0 + 2)) * 32 + co) * KC_STRIDE;
      const float* K3 = ws + ((cp * 5 + casef(q0 + 3)) * 32 + co) * KC_STRIDE;
      float z0 = K0[25], z1 = K1[25], z2 = K2[25], z3 = K3[25];
#pragma unroll
      for (int u = 0; u < 5; ++u) {
        const float* xr = &xp[(k + u) * 68 + q0];
        float4 xa = *reinterpret_cast<const float4*>(xr);
        float4 xc = *reinterpret_cast<const float4*>(xr + 4);
        float xv[8] = {xa.x, xa.y, xa.z, xa.w, xc.x, xc.y, xc.z, xc.w};
#pragma unroll
        for (int v = 0; v < 5; ++v) {
          int o = u * 5 + v;
          z0 = fmaf(xv[v], K0[o], z0);
          z1 = fmaf(xv[v + 1], K1[o], z1);
          z2 = fmaf(xv[v + 2], K2[o], z2);
          z3 = fmaf(xv[v + 3], K3[o], z3);
        }
      }
      *reinterpret_cast<float4*>(&S[co4 * SP + (k << 6) + q0]) =
          make_float4(z0, z1, z2, z3);
    }
    // ---- drain-free barrier: LDS visibility only; dump stores stay in flight ----
    asm volatile("s_waitcnt lgkmcnt(0)" ::: "memory");
    __builtin_amdgcn_s_barrier();
    // ---- dump: wave w -> plane w (8 KB contiguous), NONTEMPORAL stores ----
    {
      int co = (s << 2) + wave;
      float* dst = outb + (((size_t)co) << 12) + (r0 << 6);
#pragma unroll
      for (int i = 0; i < 8; ++i) {
        int idx4 = (i << 6) + lane;
        int k = idx4 >> 4, q0 = (idx4 & 15) << 2;
        unsigned bits = (unsigned)(Rm[k] >> q0) & 0xFu;
        floatx4 v = *reinterpret_cast<const floatx4*>(&S[wave * SP + (idx4 << 2)]);
        if (!(bits & 1u)) v.x = 0.f;
        if (!(bits & 2u)) v.y = 0.f;
        if (!(bits & 4u)) v.z = 0.f;
        if (!(bits & 8u)) v.w = 0.f;
        __builtin_nontemporal_store(v, reinterpret_cast<floatx4*>(dst + (idx4 << 2)));
      }
    }
    // ---- second drain-free barrier: protect S overwrite (WAR) next stage ----
    asm volatile("s_waitcnt lgkmcnt(0)" ::: "memory");
    __builtin_amdgcn_s_barrier();
  }
}

extern "C" void kernel_launch(void* const* d_in, const int* in_sizes, int n_in,
                              void* d_out, int out_size, void* d_ws, size_t ws_size,
                              hipStream_t stream) {
  const float* x  = (const float*)d_in[0];
  const float* W1 = (const float*)d_in[1];
  const float* b1 = (const float*)d_in[2];
  const float* W2 = (const float*)d_in[3];
  const float* b2 = (const float*)d_in[4];
  float* out = (float*)d_out;
  float* ws  = (float*)d_ws;
  int B = in_sizes[0] / 4096;  // 1024 images of 64x64x1

  hipLaunchKernelGGL(prep_kernel, dim3(25), dim3(BDIM), 0, stream, W1, b1, W2, b2, ws);
  hipLaunchKernelGGL(main_kernel, dim3(2 * B), dim3(BDIM), 0, stream, x, ws, out);
}